// Round 1
// baseline (236.628 us; speedup 1.0000x reference)
//
#include <hip/hip_runtime.h>

// Problem constants
#define BN 32768
#define KN 5
#define LN 128
#define EN 16
#define HN 3
#define ROWS (BN*KN)        // 163840
#define BK (BN*KN)
#define MT 32               // rows per tile
#define TILES (ROWS/MT)     // 5120
#define WGS 512
#define TPW (TILES/WGS)     // 10 tiles per workgroup
#define THREADS 512         // 8 waves
#define ASTR 168            // A-buf row stride in bf16 elems (160 used + 8 pad; 336B = 21*16B aligned)
#define HSTR 132            // fp32 h buffer stride (pad for banks)

using bf16x8 = __attribute__((ext_vector_type(8))) __bf16;
using f32x4  = __attribute__((ext_vector_type(4))) float;
using u16x8  = __attribute__((ext_vector_type(8))) unsigned short;

__device__ inline unsigned short f2bf(float x) {
    union { float f; unsigned u; } v; v.f = x;
    unsigned r = v.u + 0x7FFFu + ((v.u >> 16) & 1u);   // RNE
    return (unsigned short)(r >> 16);
}
__device__ inline float sigm(float x) {
    return __builtin_amdgcn_rcpf(1.0f + __builtin_amdgcn_exp2f(-1.44269504089f * x));
}
__device__ inline float tanh_(float x) {
    // (e^{2x}-1)/(e^{2x}+1); saturates correctly at +-inf
    return 1.0f - 2.0f * __builtin_amdgcn_rcpf(1.0f + __builtin_amdgcn_exp2f(2.88539008178f * x));
}
__device__ inline f32x4 splat4(float x) { f32x4 r; r[0]=x; r[1]=x; r[2]=x; r[3]=x; return r; }

__global__ __launch_bounds__(THREADS, 2)
void wahead_kernel(const float* __restrict__ z,   const float* __restrict__ anchors,
                   const float* __restrict__ W1,  const float* __restrict__ b1,
                   const float* __restrict__ W2,  const float* __restrict__ b2,
                   const float* __restrict__ Wih, const float* __restrict__ Whh,
                   const float* __restrict__ bih, const float* __restrict__ bhh,
                   const float* __restrict__ Wp,  const float* __restrict__ bp,
                   const float* __restrict__ Wr,  const float* __restrict__ br,
                   float* __restrict__ out)
{
    __shared__ unsigned short sA[2 * MT * ASTR];   // ping-pong [emb(16)|h(128)|0(16)] bf16
    __shared__ float sHf[MT * HSTR];               // final-step h, fp32
    __shared__ float sW1[32], sb1[16], sW2[256], sb2[16], sWp[128], sWr[384];

    const int tid  = threadIdx.x;
    const int wv   = tid >> 6;       // wave 0..7: owns l in [wv*16, wv*16+16)
    const int lane = tid & 63;
    const int quad = lane >> 4;
    const int cc   = lane & 15;

    // ---- stage small constant weights into LDS ----
    if (tid < 32)  sW1[tid] = W1[tid];
    if (tid < 16)  { sb1[tid] = b1[tid]; sb2[tid] = b2[tid]; }
    if (tid < 256) sW2[tid] = W2[tid];
    if (tid < 128) sWp[tid] = Wp[tid];
    if (tid < 384) sWr[tid] = Wr[tid];

    // ---- load stacked-B fragments [W_ih | W_hh | 0] as bf16 into VGPRs ----
    // B-operand layout (16x16x32): n = lane&15, k = quad*8 + j
    bf16x8 Bf[4][5];
    float biasv[4];
    #pragma unroll
    for (int t = 0; t < 4; ++t) {                      // t = gate (i,f,g,o)
        const int n = t * 128 + wv * 16 + cc;          // gate column index in [0,512)
        biasv[t] = bih[n] + bhh[n];
        #pragma unroll
        for (int kt = 0; kt < 5; ++kt) {
            const int k0 = kt * 32 + quad * 8;         // stacked-k base for this lane's 8 elems
            float v[8];
            if (k0 < 16) {                             // W_ih region (k0 in {0,8})
                const float4 p0 = *reinterpret_cast<const float4*>(Wih + n * 16 + k0);
                const float4 p1 = *reinterpret_cast<const float4*>(Wih + n * 16 + k0 + 4);
                v[0]=p0.x; v[1]=p0.y; v[2]=p0.z; v[3]=p0.w;
                v[4]=p1.x; v[5]=p1.y; v[6]=p1.z; v[7]=p1.w;
            } else if (k0 < 144) {                     // W_hh region
                const float4 p0 = *reinterpret_cast<const float4*>(Whh + n * 128 + (k0 - 16));
                const float4 p1 = *reinterpret_cast<const float4*>(Whh + n * 128 + (k0 - 16) + 4);
                v[0]=p0.x; v[1]=p0.y; v[2]=p0.z; v[3]=p0.w;
                v[4]=p1.x; v[5]=p1.y; v[6]=p1.z; v[7]=p1.w;
            } else {                                   // zero pad k in [144,160)
                #pragma unroll
                for (int j = 0; j < 8; ++j) v[j] = 0.0f;
            }
            union { bf16x8 bv; unsigned short us[8]; } pk;
            #pragma unroll
            for (int j = 0; j < 8; ++j) pk.us[j] = f2bf(v[j]);
            Bf[t][kt] = pk.bv;
        }
    }

    const float bpv = bp[0];
    const float br0 = br[0], br1 = br[1], br2 = br[2];

    __syncthreads();   // consts staged

    const int erow = tid >> 4;   // 0..31
    const int esub = tid & 15;   // 0..15

    for (int ti = 0; ti < TPW; ++ti) {
        const int tile = blockIdx.x * TPW + ti;
        const int r0g  = tile * MT;

        // ---------------- staging: emb MLP + z -> A buffers ----------------
        {
            const int gr = r0g + erow;
            // anchor embedding: thread computes one emb column (esub) of its row
            const float ax = anchors[gr * 2], ay = anchors[gr * 2 + 1];
            float acc_e = sb2[esub];
            #pragma unroll
            for (int hh = 0; hh < 16; ++hh) {
                float pre = fmaf(sW1[hh * 2], ax, fmaf(sW1[hh * 2 + 1], ay, sb1[hh]));
                pre = fmaxf(pre, 0.0f);
                acc_e = fmaf(pre, sW2[esub * 16 + hh], acc_e);
            }
            const unsigned short eb = f2bf(acc_e);
            sA[0 * MT * ASTR + erow * ASTR + esub] = eb;        // emb in both buffers
            sA[1 * MT * ASTR + erow * ASTR + esub] = eb;
            sA[0 * MT * ASTR + erow * ASTR + 144 + esub] = 0;   // zero k-pad cols
            sA[1 * MT * ASTR + erow * ASTR + 144 + esub] = 0;
            // initial h = z[b] (bf16) into buffer 0, cols 16..143
            const unsigned b_idx = (unsigned)gr / 5u;
            const float4* zp = reinterpret_cast<const float4*>(z + (size_t)b_idx * 128 + esub * 8);
            const float4 z0 = zp[0], z1 = zp[1];
            union { u16x8 v; unsigned short us[8]; } zz;
            zz.us[0]=f2bf(z0.x); zz.us[1]=f2bf(z0.y); zz.us[2]=f2bf(z0.z); zz.us[3]=f2bf(z0.w);
            zz.us[4]=f2bf(z1.x); zz.us[5]=f2bf(z1.y); zz.us[6]=f2bf(z1.z); zz.us[7]=f2bf(z1.w);
            *reinterpret_cast<u16x8*>(&sA[0 * MT * ASTR + erow * ASTR + 16 + esub * 8]) = zz.v;
        }

        float cst[2][4] = {{0,0,0,0},{0,0,0,0}};   // c state per lane

        #pragma unroll
        for (int s = 0; s < HN; ++s) {
            const int cur = s & 1;
            const int nxt = cur ^ 1;
            __syncthreads();   // staging / previous-step writes visible

            f32x4 acc[2][4];
            #pragma unroll
            for (int mt = 0; mt < 2; ++mt)
                #pragma unroll
                for (int t = 0; t < 4; ++t)
                    acc[mt][t] = splat4(biasv[t]);   // gates start at b_ih + b_hh

            #pragma unroll
            for (int kt = 0; kt < 5; ++kt) {
                // A-operand layout: m = lane&15, k = quad*8 + j  (16B-aligned ds_read_b128)
                const bf16x8 a0 = *reinterpret_cast<const bf16x8*>(
                    &sA[cur * MT * ASTR + cc * ASTR + kt * 32 + quad * 8]);
                const bf16x8 a1 = *reinterpret_cast<const bf16x8*>(
                    &sA[cur * MT * ASTR + (16 + cc) * ASTR + kt * 32 + quad * 8]);
                #pragma unroll
                for (int t = 0; t < 4; ++t) {
                    acc[0][t] = __builtin_amdgcn_mfma_f32_16x16x32_bf16(a0, Bf[t][kt], acc[0][t], 0, 0, 0);
                    acc[1][t] = __builtin_amdgcn_mfma_f32_16x16x32_bf16(a1, Bf[t][kt], acc[1][t], 0, 0, 0);
                }
            }

            // LSTM pointwise; C/D layout: col = lane&15 (-> l), row = quad*4 + reg
            const int lcol = wv * 16 + cc;
            #pragma unroll
            for (int mt = 0; mt < 2; ++mt) {
                #pragma unroll
                for (int r = 0; r < 4; ++r) {
                    const float ig = sigm(acc[mt][0][r]);
                    const float fg = sigm(acc[mt][1][r]);
                    const float gg = tanh_(acc[mt][2][r]);
                    const float og = sigm(acc[mt][3][r]);
                    const float cn = fmaf(fg, cst[mt][r], ig * gg);
                    cst[mt][r] = cn;
                    const float hn = og * tanh_(cn);
                    const int m = mt * 16 + quad * 4 + r;
                    if (s == HN - 1) {
                        sHf[m * HSTR + lcol] = hn;                       // fp32 for epilogue
                    } else {
                        sA[nxt * MT * ASTR + m * ASTR + 16 + lcol] = f2bf(hn);
                    }
                }
            }
        }

        __syncthreads();   // sHf complete

        // ---------------- epilogue: heads (fp32) ----------------
        {
            const int row = tid >> 4;    // 0..31
            const int j   = tid & 15;    // 16 threads per row, 8 l each
            float p = 0.f, q0 = 0.f, q1 = 0.f, q2 = 0.f;
            #pragma unroll
            for (int u = 0; u < 8; ++u) {
                const int l = j * 8 + u;
                const float hv = sHf[row * HSTR + l];
                p  = fmaf(hv, sWp[l], p);
                q0 = fmaf(hv, sWr[l], q0);
                q1 = fmaf(hv, sWr[128 + l], q1);
                q2 = fmaf(hv, sWr[256 + l], q2);
            }
            #pragma unroll
            for (int m = 1; m < 16; m <<= 1) {
                p  += __shfl_xor(p,  m, 64);
                q0 += __shfl_xor(q0, m, 64);
                q1 += __shfl_xor(q1, m, 64);
                q2 += __shfl_xor(q2, m, 64);
            }
            if (j == 0) {
                const int gr = r0g + row;
                const float prog  = p + bpv;
                const float rr0 = q0 + br0, rr1 = q1 + br1, rr2 = q2 + br2;
                const float rmean = (rr0 + rr1 + rr2) * (1.0f / 3.0f);
                const float s0 = sigm(rr0), s1 = sigm(rr1), s2 = sigm(rr2);
                const float sm = (s0 + s1 + s2) * (1.0f / 3.0f);
                const float d0 = s0 - sm, d1 = s1 - sm, d2 = s2 - sm;
                const float unc = (d0 * d0 + d1 * d1 + d2 * d2) * 0.5f;   // ddof=1, ENS=3
                out[gr]          = rmean;
                out[BK + gr]     = prog;
                out[2 * BK + gr] = unc;
                out[3 * BK + gr] = rr0;
                out[4 * BK + gr] = rr1;
                out[5 * BK + gr] = rr2;
            }
        }
        // next staging writes disjoint LDS regions (sA emb/z); step-0 barrier protects reads
    }
}

extern "C" void kernel_launch(void* const* d_in, const int* in_sizes, int n_in,
                              void* d_out, int out_size, void* d_ws, size_t ws_size,
                              hipStream_t stream) {
    const float* z       = (const float*)d_in[0];
    const float* anchors = (const float*)d_in[1];
    const float* W1      = (const float*)d_in[2];
    const float* b1      = (const float*)d_in[3];
    const float* W2      = (const float*)d_in[4];
    const float* b2      = (const float*)d_in[5];
    const float* Wih     = (const float*)d_in[6];
    const float* Whh     = (const float*)d_in[7];
    const float* bih     = (const float*)d_in[8];
    const float* bhh     = (const float*)d_in[9];
    const float* Wp      = (const float*)d_in[10];
    const float* bp      = (const float*)d_in[11];
    const float* Wr      = (const float*)d_in[12];
    const float* br      = (const float*)d_in[13];

    hipLaunchKernelGGL(wahead_kernel, dim3(WGS), dim3(THREADS), 0, stream,
                       z, anchors, W1, b1, W2, b2, Wih, Whh, bih, bhh,
                       Wp, bp, Wr, br, (float*)d_out);
}